// Round 1
// baseline (324.521 us; speedup 1.0000x reference)
//
#include <hip/hip_runtime.h>
#include <math.h>

// HyperbolicGRUCell: B=32768, I=H=512, c=0.01 (sqrt_c = 0.1)
// R6: counted-vmcnt half-stage pipeline (T3+T4 port).
//   Each BK=32 stage splits into X-half {x-A, Wih r/z/n} and H-half
//   {h-A, Whh r/z/n}, 20KB each -> 4 half-buffers in 80KB LDS, 2-deep
//   prefetch, 5 gload_lds/wave/half. Steady loop waits vmcnt(5) (never 0),
//   keeping 5 loads in flight across every barrier; only the last half-stage
//   drains vmcnt(0). One barrier per half-stage (overwrite victim consumed
//   two half-stages earlier; barrier s-1 separates).
//   1) prep_kernel : log-map + bf16 cvt -> ws chunks [kc][row]
//   2) wcvt_kernel : W fp32 -> bf16 in staging order [cb][kb][g][q][n]
//   3) gru_gemm    : BM=128 BN=64, 4 waves 2m x 2n, 4 merged acc families
//   4) expmap      : in-place exp-map on out

typedef __attribute__((ext_vector_type(8))) short bf16x8;
typedef __attribute__((ext_vector_type(8))) unsigned short u16x8;
typedef __attribute__((ext_vector_type(4))) float f32x4;

__device__ __forceinline__ unsigned short f2bf(float f) {
    unsigned int u = __float_as_uint(f);
    u += 0x7FFFu + ((u >> 16) & 1u);
    return (unsigned short)(u >> 16);
}

__device__ __forceinline__ u16x8 cvt8(float4 v0, float4 v1, float s) {
    u16x8 r;
    r[0] = f2bf(v0.x * s); r[1] = f2bf(v0.y * s); r[2] = f2bf(v0.z * s); r[3] = f2bf(v0.w * s);
    r[4] = f2bf(v1.x * s); r[5] = f2bf(v1.y * s); r[6] = f2bf(v1.z * s); r[7] = f2bf(v1.w * s);
    return r;
}

__device__ __forceinline__ void gload16_lds(const void* g, void* l) {
    __builtin_amdgcn_global_load_lds(
        (const __attribute__((address_space(1))) unsigned int*)g,
        (__attribute__((address_space(3))) unsigned int*)l, 16, 0, 0);
}

__device__ __forceinline__ float sigm(float v) { return 1.f / (1.f + __expf(-v)); }
__device__ __forceinline__ float tanh_fast(float v) { return 1.f - 2.f / (__expf(2.f * v) + 1.f); }

// ---------------------------------------------------------------------------
// 1) prep: 32 rows/block, 8 lanes/row; coalesced reads, LDS transpose so the
//    [kc][row] chunk writes are 512B-contiguous runs.
// ---------------------------------------------------------------------------
__global__ void prep_kernel(const float* __restrict__ x, const float* __restrict__ h,
                            u16x8* __restrict__ xt, u16x8* __restrict__ ht,
                            float* __restrict__ mh, int B) {
    __shared__ u16x8 lbuf[32 * 65];
    int t = threadIdx.x;
    int row = t >> 3, c8 = t & 7;
    int r0 = blockIdx.x * 32;
    bool is_h = (blockIdx.y == 1);
    const float* src = is_h ? h : x;
    const float4* p4 = (const float4*)src + (size_t)(r0 + row) * 128;

    float4 v[8][2];
    float s = 0.f;
    #pragma unroll
    for (int i = 0; i < 8; ++i) {
        int j = i * 16 + c8 * 2;
        v[i][0] = p4[j]; v[i][1] = p4[j + 1];
        s += v[i][0].x * v[i][0].x + v[i][0].y * v[i][0].y + v[i][0].z * v[i][0].z + v[i][0].w * v[i][0].w
           + v[i][1].x * v[i][1].x + v[i][1].y * v[i][1].y + v[i][1].z * v[i][1].z + v[i][1].w * v[i][1].w;
    }
    #pragma unroll
    for (int off = 4; off; off >>= 1) s += __shfl_xor(s, off);
    float norm = fmaxf(sqrtf(s), 1e-15f);
    float a = fminf(0.1f * norm, 1.f - 1e-5f);
    float m = 0.5f * (log1pf(a) - log1pf(-a)) / (0.1f * norm);

    #pragma unroll
    for (int i = 0; i < 8; ++i)
        lbuf[row * 65 + i * 8 + c8] = cvt8(v[i][0], v[i][1], m);
    if (is_h && c8 == 0) mh[r0 + row] = m;
    __syncthreads();

    u16x8* dst = is_h ? ht : xt;
    #pragma unroll
    for (int it = 0; it < 8; ++it) {
        int u = it * 256 + t;
        int rr = u & 31, kc = u >> 5;
        dst[(size_t)kc * B + r0 + rr] = lbuf[rr * 65 + kc];
    }
}

// ---------------------------------------------------------------------------
// 2) weight cvt+permute: chunk C = (cb*16+kb)*1536 + g*256 + q*64 + n
// ---------------------------------------------------------------------------
__global__ void wcvt_kernel(const float* __restrict__ Wih, const float* __restrict__ Whh,
                            u16x8* __restrict__ wst) {
    int C = blockIdx.x * 256 + threadIdx.x;
    int n  = C & 63;
    int q  = (C >> 6) & 3;
    int t2 = C >> 8;
    int g  = t2 % 6;
    int t3 = t2 / 6;
    int kb = t3 & 15;
    int cb = t3 >> 4;
    const float* src = (g < 3) ? Wih : Whh;
    int grow = (g % 3) * 512 + cb * 64 + n;
    int col0 = kb * 32 + q * 8;
    const float4* p = (const float4*)(src + (size_t)grow * 512 + col0);
    wst[C] = cvt8(p[0], p[1], 1.f);
}

// ---------------------------------------------------------------------------
// 3) fused dual-GEMM + GRU, counted-vmcnt half-stage pipeline.
//    80 KB LDS = 4 half-buffers x 1280 chunks; half-buffer layout:
//      [0,512)    A chunks [q(4)][row(128)]   (x for X-half, h for H-half)
//      [512,1280) W chunks [g'(3)][q(4)][n(64)]
//    Sub-iter s (s = 2*kb + half): wait vmcnt(5); issue stage(s+2);
//    barrier; ds_read + 24 MFMA on buffer s%4.
// ---------------------------------------------------------------------------
__launch_bounds__(256, 2)
__global__ void gru_gemm_kernel(const u16x8* __restrict__ xt, const u16x8* __restrict__ ht,
                                const u16x8* __restrict__ wst,
                                const float* __restrict__ h, const float* __restrict__ mh,
                                const float* __restrict__ bih, const float* __restrict__ bhh,
                                float* __restrict__ out, int B) {
    __shared__ u16x8 lds[5120];                 // 80 KB

    int t = threadIdx.x;
    int w = t >> 6, lane = t & 63;
    int quad = lane >> 4, lr = lane & 15;
    int wm = w >> 1, wn = w & 1;
    int r0 = blockIdx.x * 128;                  // row-group fastest
    int cb = blockIdx.y;

    // staging sources: wave w stages A q=w (2 loads) + W chunks [w*192, w*192+192)
    const u16x8* pax = xt + (size_t)w * B + r0 + lane;
    const u16x8* pah = ht + (size_t)w * B + r0 + lane;
    const u16x8* pwb = wst + (size_t)cb * 24576 + w * 192 + lane;

    f32x4 aR[4][2], aZ[4][2], aNi[4][2], aNh[4][2];
    #pragma unroll
    for (int rh = 0; rh < 4; ++rh)
        #pragma unroll
        for (int ch = 0; ch < 2; ++ch) {
            aR[rh][ch]  = (f32x4){0.f, 0.f, 0.f, 0.f};
            aZ[rh][ch]  = (f32x4){0.f, 0.f, 0.f, 0.f};
            aNi[rh][ch] = (f32x4){0.f, 0.f, 0.f, 0.f};
            aNh[rh][ch] = (f32x4){0.f, 0.f, 0.f, 0.f};
        }

    // issue one half-stage: 5 gload_lds per wave (2 A + 3 W)
    auto stage = [&](int kb, int half, int bidx) {
        u16x8* hb = lds + bidx * 1280;
        const u16x8* pa = (half ? pah : pax) + (size_t)kb * 4 * B;
        gload16_lds(pa,      hb + w * 128);
        gload16_lds(pa + 64, hb + w * 128 + 64);
        const u16x8* pq = pwb + (size_t)kb * 1536 + half * 768;
        gload16_lds(pq,       hb + 512 + w * 192);
        gload16_lds(pq + 64,  hb + 512 + w * 192 + 64);
        gload16_lds(pq + 128, hb + 512 + w * 192 + 128);
    };

    // consume one half-buffer: 10 ds_read_b128 + 24 MFMA.
    // accN = aNi for X-half (Wih n-gate), aNh for H-half (Whh n-gate).
    auto consume = [&](int bidx, f32x4 (&accN)[4][2]) {
        const u16x8* hb = lds + bidx * 1280;
        bf16x8 av[4], wv[3][2];
        #pragma unroll
        for (int rh = 0; rh < 4; ++rh)
            av[rh] = *(const bf16x8*)&hb[quad * 128 + wm * 64 + rh * 16 + lr];
        #pragma unroll
        for (int g = 0; g < 3; ++g) {
            int c = 512 + g * 256 + quad * 64 + wn * 32 + lr;
            wv[g][0] = *(const bf16x8*)&hb[c];
            wv[g][1] = *(const bf16x8*)&hb[c + 16];
        }
        #pragma unroll
        for (int rh = 0; rh < 4; ++rh)
            #pragma unroll
            for (int ch = 0; ch < 2; ++ch) {
                aR[rh][ch]   = __builtin_amdgcn_mfma_f32_16x16x32_bf16(av[rh], wv[0][ch], aR[rh][ch], 0, 0, 0);
                aZ[rh][ch]   = __builtin_amdgcn_mfma_f32_16x16x32_bf16(av[rh], wv[1][ch], aZ[rh][ch], 0, 0, 0);
                accN[rh][ch] = __builtin_amdgcn_mfma_f32_16x16x32_bf16(av[rh], wv[2][ch], accN[rh][ch], 0, 0, 0);
            }
    };

    // prologue: half-stages 0 (x) and 1 (h) of kb=0 -> buffers 0,1
    stage(0, 0, 0);
    stage(0, 1, 1);

    for (int kb = 0; kb < 15; ++kb) {
        int p = (kb & 1) * 2;
        // X half (s = 2kb): drain loads(s), keep loads(s+1) in flight
        asm volatile("s_waitcnt vmcnt(5)" ::: "memory");
        stage(kb + 1, 0, p ^ 2);
        __builtin_amdgcn_s_barrier();
        asm volatile("" ::: "memory");
        consume(p, aNi);

        // H half (s = 2kb+1)
        asm volatile("s_waitcnt vmcnt(5)" ::: "memory");
        stage(kb + 1, 1, (p ^ 2) + 1);
        __builtin_amdgcn_s_barrier();
        asm volatile("" ::: "memory");
        consume(p + 1, aNh);
    }
    // kb = 15 (buffers 2,3): no prefetch; last half drains to 0
    asm volatile("s_waitcnt vmcnt(5)" ::: "memory");
    __builtin_amdgcn_s_barrier();
    asm volatile("" ::: "memory");
    consume(2, aNi);

    asm volatile("s_waitcnt vmcnt(0)" ::: "memory");
    __builtin_amdgcn_s_barrier();
    asm volatile("" ::: "memory");
    consume(3, aNh);

    // epilogue: C/D layout col=lane&15, row=quad*4+reg
    #pragma unroll
    for (int ch = 0; ch < 2; ++ch) {
        int col = cb * 64 + wn * 32 + ch * 16 + lr;
        float br  = bih[col] + bhh[col];
        float bz  = bih[512 + col] + bhh[512 + col];
        float bin = bih[1024 + col];
        float bhn = bhh[1024 + col];
        #pragma unroll
        for (int rh = 0; rh < 4; ++rh)
            #pragma unroll
            for (int reg = 0; reg < 4; ++reg) {
                int row = r0 + wm * 64 + rh * 16 + quad * 4 + reg;
                float rg = sigm(aR[rh][ch][reg] + br);
                float zg = sigm(aZ[rh][ch][reg] + bz);
                float ng = tanh_fast(aNi[rh][ch][reg] + bin + rg * (aNh[rh][ch][reg] + bhn));
                float ht_ = mh[row] * h[(size_t)row * 512 + col];
                out[(size_t)row * 512 + col] = (1.f - zg) * ng + zg * ht_;
            }
    }
}

// ---------------------------------------------------------------------------
// 4) exp-map in place
// ---------------------------------------------------------------------------
__global__ void expmap_kernel(float* __restrict__ out, int D) {
    int wave = threadIdx.x >> 6;
    int lane = threadIdx.x & 63;
    int row = blockIdx.x * 4 + wave;
    float4* p = (float4*)(out + (size_t)row * D);
    float4 v0 = p[lane], v1 = p[lane + 64];
    float s = v0.x * v0.x + v0.y * v0.y + v0.z * v0.z + v0.w * v0.w
            + v1.x * v1.x + v1.y * v1.y + v1.z * v1.z + v1.w * v1.w;
    #pragma unroll
    for (int off = 32; off; off >>= 1) s += __shfl_xor(s, off);
    float norm = fmaxf(sqrtf(s), 1e-15f);
    float a = 0.1f * norm;
    float m = tanhf(a) / a;
    v0.x *= m; v0.y *= m; v0.z *= m; v0.w *= m;
    v1.x *= m; v1.y *= m; v1.z *= m; v1.w *= m;
    p[lane] = v0;
    p[lane + 64] = v1;
}

extern "C" void kernel_launch(void* const* d_in, const int* in_sizes, int n_in,
                              void* d_out, int out_size, void* d_ws, size_t ws_size,
                              hipStream_t stream) {
    const float* x   = (const float*)d_in[0];
    const float* h   = (const float*)d_in[1];
    const float* Wih = (const float*)d_in[2];
    const float* Whh = (const float*)d_in[3];
    const float* bih = (const float*)d_in[4];
    const float* bhh = (const float*)d_in[5];
    float* out = (float*)d_out;

    int H = in_sizes[4] / 3;          // 512
    int I = in_sizes[2] / (3 * H);    // 512
    int B = in_sizes[0] / I;          // 32768

    u16x8* xt  = (u16x8*)d_ws;
    u16x8* ht  = xt + (size_t)64 * B;
    u16x8* wst = ht + (size_t)64 * B;
    float* mh  = (float*)(wst + 196608);

    prep_kernel<<<dim3(B / 32, 2), 256, 0, stream>>>(x, h, xt, ht, mh, B);
    wcvt_kernel<<<768, 256, 0, stream>>>(Wih, Whh, wst);
    gru_gemm_kernel<<<dim3(B / 128, 8), 256, 0, stream>>>(xt, ht, wst, h, mh, bih, bhh, out, B);
    expmap_kernel<<<B / 4, 256, 0, stream>>>(out, H);
}

// Round 2
// 317.788 us; speedup vs baseline: 1.0212x; 1.0212x over previous
//
#include <hip/hip_runtime.h>
#include <math.h>

// HyperbolicGRUCell: B=32768, I=H=512, c=0.01 (sqrt_c = 0.1)
// R7: frag-level software pipeline on top of R6's counted-vmcnt half-stages.
//   Diagnosis (R6 counters): MfmaUtil 35.6%, LDS reads (80KB/CU/half-stage
//   ~940cyc) and MFMA (~930cyc) each ~50us total but serialized by the
//   in-sub-iter read->MFMA dependency -> 122us. Fix: at sub-iter s, ds_read
//   buffer s into frag set (s&1) and MFMA the set read at s-1. LDS pipe and
//   MFMA pipe now overlap across sub-iters.
//   Safety: s_waitcnt vmcnt(5) lgkmcnt(10) before each barrier ensures
//   reads of s-2 complete (only s-1's 10 may be outstanding) before any
//   wave's stage overwrites that buffer. T5 setprio around MFMA cluster.
//   1) prep_kernel : log-map + bf16 cvt -> ws chunks [kc][row]
//   2) wcvt_kernel : W fp32 -> bf16 in staging order [cb][kb][g][q][n]
//   3) gru_gemm    : BM=128 BN=64, 4 waves 2m x 2n, 4 merged acc families
//   4) expmap      : in-place exp-map on out

typedef __attribute__((ext_vector_type(8))) short bf16x8;
typedef __attribute__((ext_vector_type(8))) unsigned short u16x8;
typedef __attribute__((ext_vector_type(4))) float f32x4;

__device__ __forceinline__ unsigned short f2bf(float f) {
    unsigned int u = __float_as_uint(f);
    u += 0x7FFFu + ((u >> 16) & 1u);
    return (unsigned short)(u >> 16);
}

__device__ __forceinline__ u16x8 cvt8(float4 v0, float4 v1, float s) {
    u16x8 r;
    r[0] = f2bf(v0.x * s); r[1] = f2bf(v0.y * s); r[2] = f2bf(v0.z * s); r[3] = f2bf(v0.w * s);
    r[4] = f2bf(v1.x * s); r[5] = f2bf(v1.y * s); r[6] = f2bf(v1.z * s); r[7] = f2bf(v1.w * s);
    return r;
}

__device__ __forceinline__ void gload16_lds(const void* g, void* l) {
    __builtin_amdgcn_global_load_lds(
        (const __attribute__((address_space(1))) unsigned int*)g,
        (__attribute__((address_space(3))) unsigned int*)l, 16, 0, 0);
}

__device__ __forceinline__ float sigm(float v) { return 1.f / (1.f + __expf(-v)); }
__device__ __forceinline__ float tanh_fast(float v) { return 1.f - 2.f / (__expf(2.f * v) + 1.f); }

// ---------------------------------------------------------------------------
// 1) prep: 32 rows/block, 8 lanes/row; coalesced reads, LDS transpose so the
//    [kc][row] chunk writes are 512B-contiguous runs.
// ---------------------------------------------------------------------------
__global__ void prep_kernel(const float* __restrict__ x, const float* __restrict__ h,
                            u16x8* __restrict__ xt, u16x8* __restrict__ ht,
                            float* __restrict__ mh, int B) {
    __shared__ u16x8 lbuf[32 * 65];
    int t = threadIdx.x;
    int row = t >> 3, c8 = t & 7;
    int r0 = blockIdx.x * 32;
    bool is_h = (blockIdx.y == 1);
    const float* src = is_h ? h : x;
    const float4* p4 = (const float4*)src + (size_t)(r0 + row) * 128;

    float4 v[8][2];
    float s = 0.f;
    #pragma unroll
    for (int i = 0; i < 8; ++i) {
        int j = i * 16 + c8 * 2;
        v[i][0] = p4[j]; v[i][1] = p4[j + 1];
        s += v[i][0].x * v[i][0].x + v[i][0].y * v[i][0].y + v[i][0].z * v[i][0].z + v[i][0].w * v[i][0].w
           + v[i][1].x * v[i][1].x + v[i][1].y * v[i][1].y + v[i][1].z * v[i][1].z + v[i][1].w * v[i][1].w;
    }
    #pragma unroll
    for (int off = 4; off; off >>= 1) s += __shfl_xor(s, off);
    float norm = fmaxf(sqrtf(s), 1e-15f);
    float a = fminf(0.1f * norm, 1.f - 1e-5f);
    float m = 0.5f * (log1pf(a) - log1pf(-a)) / (0.1f * norm);

    #pragma unroll
    for (int i = 0; i < 8; ++i)
        lbuf[row * 65 + i * 8 + c8] = cvt8(v[i][0], v[i][1], m);
    if (is_h && c8 == 0) mh[r0 + row] = m;
    __syncthreads();

    u16x8* dst = is_h ? ht : xt;
    #pragma unroll
    for (int it = 0; it < 8; ++it) {
        int u = it * 256 + t;
        int rr = u & 31, kc = u >> 5;
        dst[(size_t)kc * B + r0 + rr] = lbuf[rr * 65 + kc];
    }
}

// ---------------------------------------------------------------------------
// 2) weight cvt+permute: chunk C = (cb*16+kb)*1536 + g*256 + q*64 + n
// ---------------------------------------------------------------------------
__global__ void wcvt_kernel(const float* __restrict__ Wih, const float* __restrict__ Whh,
                            u16x8* __restrict__ wst) {
    int C = blockIdx.x * 256 + threadIdx.x;
    int n  = C & 63;
    int q  = (C >> 6) & 3;
    int t2 = C >> 8;
    int g  = t2 % 6;
    int t3 = t2 / 6;
    int kb = t3 & 15;
    int cb = t3 >> 4;
    const float* src = (g < 3) ? Wih : Whh;
    int grow = (g % 3) * 512 + cb * 64 + n;
    int col0 = kb * 32 + q * 8;
    const float4* p = (const float4*)(src + (size_t)grow * 512 + col0);
    wst[C] = cvt8(p[0], p[1], 1.f);
}

// ---------------------------------------------------------------------------
// 3) fused dual-GEMM + GRU, pipelined half-stages.
//    80 KB LDS = 4 half-buffers x 1280 chunks; half-buffer layout:
//      [0,512)    A chunks [q(4)][row(128)]   (x for X-half, h for H-half)
//      [512,1280) W chunks [g'(3)][q(4)][n(64)]
//    Sub-iter s: wait vmcnt(5) lgkmcnt(10); barrier; ds_read buf(s%4) ->
//    frag set(s&1); issue stage(s+2); MFMA frag set((s-1)&1).
// ---------------------------------------------------------------------------
__launch_bounds__(256, 2)
__global__ void gru_gemm_kernel(const u16x8* __restrict__ xt, const u16x8* __restrict__ ht,
                                const u16x8* __restrict__ wst,
                                const float* __restrict__ h, const float* __restrict__ mh,
                                const float* __restrict__ bih, const float* __restrict__ bhh,
                                float* __restrict__ out, int B) {
    __shared__ u16x8 lds[5120];                 // 80 KB

    int t = threadIdx.x;
    int w = t >> 6, lane = t & 63;
    int quad = lane >> 4, lr = lane & 15;
    int wm = w >> 1, wn = w & 1;
    int r0 = blockIdx.x * 128;                  // row-group fastest
    int cb = blockIdx.y;

    // staging sources: wave w stages A q=w (2 loads) + W chunks [w*192, w*192+192)
    const u16x8* pax = xt + (size_t)w * B + r0 + lane;
    const u16x8* pah = ht + (size_t)w * B + r0 + lane;
    const u16x8* pwb = wst + (size_t)cb * 24576 + w * 192 + lane;

    f32x4 aR[4][2], aZ[4][2], aNi[4][2], aNh[4][2];
    #pragma unroll
    for (int rh = 0; rh < 4; ++rh)
        #pragma unroll
        for (int ch = 0; ch < 2; ++ch) {
            aR[rh][ch]  = (f32x4){0.f, 0.f, 0.f, 0.f};
            aZ[rh][ch]  = (f32x4){0.f, 0.f, 0.f, 0.f};
            aNi[rh][ch] = (f32x4){0.f, 0.f, 0.f, 0.f};
            aNh[rh][ch] = (f32x4){0.f, 0.f, 0.f, 0.f};
        }

    // issue one half-stage: 5 gload_lds per wave (2 A + 3 W)
    auto stage = [&](int kb, int half, int bidx) {
        u16x8* hb = lds + bidx * 1280;
        const u16x8* pa = (half ? pah : pax) + (size_t)kb * 4 * B;
        gload16_lds(pa,      hb + w * 128);
        gload16_lds(pa + 64, hb + w * 128 + 64);
        const u16x8* pq = pwb + (size_t)kb * 1536 + half * 768;
        gload16_lds(pq,       hb + 512 + w * 192);
        gload16_lds(pq + 64,  hb + 512 + w * 192 + 64);
        gload16_lds(pq + 128, hb + 512 + w * 192 + 128);
    };

    // 10 ds_read_b128 of one half-buffer into a frag set
    auto read_frags = [&](int bidx, bf16x8 (&av)[4], bf16x8 (&wv)[3][2]) {
        const u16x8* hb = lds + bidx * 1280;
        #pragma unroll
        for (int rh = 0; rh < 4; ++rh)
            av[rh] = *(const bf16x8*)&hb[quad * 128 + wm * 64 + rh * 16 + lr];
        #pragma unroll
        for (int g = 0; g < 3; ++g) {
            int c = 512 + g * 256 + quad * 64 + wn * 32 + lr;
            wv[g][0] = *(const bf16x8*)&hb[c];
            wv[g][1] = *(const bf16x8*)&hb[c + 16];
        }
    };

    // 24 MFMA on a frag set. accN = aNi for X-half frags, aNh for H-half.
    auto mfma_half = [&](bf16x8 (&av)[4], bf16x8 (&wv)[3][2], f32x4 (&accN)[4][2]) {
        __builtin_amdgcn_s_setprio(1);
        #pragma unroll
        for (int rh = 0; rh < 4; ++rh)
            #pragma unroll
            for (int ch = 0; ch < 2; ++ch) {
                aR[rh][ch]   = __builtin_amdgcn_mfma_f32_16x16x32_bf16(av[rh], wv[0][ch], aR[rh][ch], 0, 0, 0);
                aZ[rh][ch]   = __builtin_amdgcn_mfma_f32_16x16x32_bf16(av[rh], wv[1][ch], aZ[rh][ch], 0, 0, 0);
                accN[rh][ch] = __builtin_amdgcn_mfma_f32_16x16x32_bf16(av[rh], wv[2][ch], accN[rh][ch], 0, 0, 0);
            }
        __builtin_amdgcn_s_setprio(0);
    };

    bf16x8 aX[4], wX[3][2];     // frag set 0 (X halves, even s)
    bf16x8 aH[4], wH[3][2];     // frag set 1 (H halves, odd s)

    // prologue: half-stages 0 (x) and 1 (h) of kb=0 -> buffers 0,1
    stage(0, 0, 0);
    stage(0, 1, 1);

    // s=0: X kb0. outstanding vm: stage0+stage1=10 -> drain stage0.
    asm volatile("s_waitcnt vmcnt(5)" ::: "memory");
    __builtin_amdgcn_s_barrier();
    asm volatile("" ::: "memory");
    read_frags(0, aX, wX);
    stage(1, 0, 2);                       // s+2 = 2

    // s=1: H kb0.
    asm volatile("s_waitcnt vmcnt(5) lgkmcnt(10)" ::: "memory");
    __builtin_amdgcn_s_barrier();
    asm volatile("" ::: "memory");
    read_frags(1, aH, wH);
    stage(1, 1, 3);                       // s+2 = 3
    mfma_half(aX, wX, aNi);               // X frags of kb0

    for (int kb = 1; kb < 15; ++kb) {
        int p = (kb & 1) * 2;             // buffer of X half: (2kb)%4
        // X half (s = 2kb)
        asm volatile("s_waitcnt vmcnt(5) lgkmcnt(10)" ::: "memory");
        __builtin_amdgcn_s_barrier();
        asm volatile("" ::: "memory");
        read_frags(p, aX, wX);
        stage(kb + 1, 0, p ^ 2);
        mfma_half(aH, wH, aNh);           // H frags of kb-1

        // H half (s = 2kb+1)
        asm volatile("s_waitcnt vmcnt(5) lgkmcnt(10)" ::: "memory");
        __builtin_amdgcn_s_barrier();
        asm volatile("" ::: "memory");
        read_frags(p + 1, aH, wH);
        stage(kb + 1, 1, (p ^ 2) + 1);
        mfma_half(aX, wX, aNi);           // X frags of kb
    }

    // kb=15, s=30: outstanding = stage(30)+stage(31) = 10 -> vmcnt(5)
    asm volatile("s_waitcnt vmcnt(5) lgkmcnt(10)" ::: "memory");
    __builtin_amdgcn_s_barrier();
    asm volatile("" ::: "memory");
    read_frags(2, aX, wX);
    mfma_half(aH, wH, aNh);               // H frags of kb14

    // s=31: outstanding = stage(31) = 5 -> vmcnt(0)
    asm volatile("s_waitcnt vmcnt(0) lgkmcnt(10)" ::: "memory");
    __builtin_amdgcn_s_barrier();
    asm volatile("" ::: "memory");
    read_frags(3, aH, wH);
    mfma_half(aX, wX, aNi);               // X frags of kb15
    mfma_half(aH, wH, aNh);               // H frags of kb15 (compiler lgkm-waits)

    // epilogue: C/D layout col=lane&15, row=quad*4+reg
    #pragma unroll
    for (int ch = 0; ch < 2; ++ch) {
        int col = cb * 64 + wn * 32 + ch * 16 + lr;
        float br  = bih[col] + bhh[col];
        float bz  = bih[512 + col] + bhh[512 + col];
        float bin = bih[1024 + col];
        float bhn = bhh[1024 + col];
        #pragma unroll
        for (int rh = 0; rh < 4; ++rh)
            #pragma unroll
            for (int reg = 0; reg < 4; ++reg) {
                int row = r0 + wm * 64 + rh * 16 + quad * 4 + reg;
                float rg = sigm(aR[rh][ch][reg] + br);
                float zg = sigm(aZ[rh][ch][reg] + bz);
                float ng = tanh_fast(aNi[rh][ch][reg] + bin + rg * (aNh[rh][ch][reg] + bhn));
                float ht_ = mh[row] * h[(size_t)row * 512 + col];
                out[(size_t)row * 512 + col] = (1.f - zg) * ng + zg * ht_;
            }
    }
}

// ---------------------------------------------------------------------------
// 4) exp-map in place
// ---------------------------------------------------------------------------
__global__ void expmap_kernel(float* __restrict__ out, int D) {
    int wave = threadIdx.x >> 6;
    int lane = threadIdx.x & 63;
    int row = blockIdx.x * 4 + wave;
    float4* p = (float4*)(out + (size_t)row * D);
    float4 v0 = p[lane], v1 = p[lane + 64];
    float s = v0.x * v0.x + v0.y * v0.y + v0.z * v0.z + v0.w * v0.w
            + v1.x * v1.x + v1.y * v1.y + v1.z * v1.z + v1.w * v1.w;
    #pragma unroll
    for (int off = 32; off; off >>= 1) s += __shfl_xor(s, off);
    float norm = fmaxf(sqrtf(s), 1e-15f);
    float a = 0.1f * norm;
    float m = tanhf(a) / a;
    v0.x *= m; v0.y *= m; v0.z *= m; v0.w *= m;
    v1.x *= m; v1.y *= m; v1.z *= m; v1.w *= m;
    p[lane] = v0;
    p[lane + 64] = v1;
}

extern "C" void kernel_launch(void* const* d_in, const int* in_sizes, int n_in,
                              void* d_out, int out_size, void* d_ws, size_t ws_size,
                              hipStream_t stream) {
    const float* x   = (const float*)d_in[0];
    const float* h   = (const float*)d_in[1];
    const float* Wih = (const float*)d_in[2];
    const float* Whh = (const float*)d_in[3];
    const float* bih = (const float*)d_in[4];
    const float* bhh = (const float*)d_in[5];
    float* out = (float*)d_out;

    int H = in_sizes[4] / 3;          // 512
    int I = in_sizes[2] / (3 * H);    // 512
    int B = in_sizes[0] / I;          // 32768

    u16x8* xt  = (u16x8*)d_ws;
    u16x8* ht  = xt + (size_t)64 * B;
    u16x8* wst = ht + (size_t)64 * B;
    float* mh  = (float*)(wst + 196608);

    prep_kernel<<<dim3(B / 32, 2), 256, 0, stream>>>(x, h, xt, ht, mh, B);
    wcvt_kernel<<<768, 256, 0, stream>>>(Wih, Whh, wst);
    gru_gemm_kernel<<<dim3(B / 128, 8), 256, 0, stream>>>(xt, ht, wst, h, mh, bih, bhh, out, B);
    expmap_kernel<<<B / 4, 256, 0, stream>>>(out, H);
}